// Round 16
// baseline (635.594 us; speedup 1.0000x reference)
//
#include <hip/hip_runtime.h>
#include <math.h>

#define BB  8
#define CH  256
#define NVT 9216        // 96*96
#define PLN (98*98*32)  // padded NC32 plane: 307328 shorts
#define PROW (98*32)    // padded row: 3136 shorts
#define NPK 12

typedef short bh8 __attribute__((ext_vector_type(8)));
typedef short bh4 __attribute__((ext_vector_type(4)));
typedef float f4  __attribute__((ext_vector_type(4)));

__device__ __forceinline__ float bf2f(ushort u) {
    union { uint i; float f; } x; x.i = ((uint)u) << 16; return x.f;
}
__device__ __forceinline__ ushort f2bf(float f) {
    union { float f; uint i; } x; x.f = f;
    uint r = (x.i + 0x7FFFu + ((x.i >> 16) & 1u)) >> 16;
    return (ushort)r;
}
__device__ __forceinline__ int cperm(int ci) {
    return 8 * ((ci >> 2) & 3) + 4 * (ci >> 4) + (ci & 3);
}
__device__ __forceinline__ void gld16(const void* g, void* l) {
    __builtin_amdgcn_global_load_lds(
        (const __attribute__((address_space(1))) void*)g,
        (__attribute__((address_space(3))) void*)l, 16, 0, 0);
}

// -------------------------------------------------------------------------
struct PackArgs {
    const float* w[NPK];
    const float* scale[NPK];
    unsigned dst[NPK];
    int cin[NPK], taps[NPK], csrc[NPK], cobase[NPK], cot[NPK], kcb[NPK];
    int start[NPK + 1];
};

// -------------------------------------------------------------------------
// ONE prep dispatch: pads + bias concat + 12 weight packs + x conversion
// -------------------------------------------------------------------------
__global__ __launch_bounds__(256) void prep_all_k(PackArgs pa,
    ushort* __restrict__ ws, const float* __restrict__ x,
    unsigned x32_off, unsigned avl_off, unsigned b3_off,
    const float* __restrict__ bq, const float* __restrict__ bk,
    const float* __restrict__ bv, int packBlocks)
{
    const int bid = blockIdx.x;
    const int tid = threadIdx.x;

    if (bid < 192) {
        int p = bid;
        ushort* base = (p < 64) ? ws + x32_off + (size_t)p * PLN
                                : ws + avl_off + (size_t)(p - 64) * PLN;
        const bh8 z = {0,0,0,0,0,0,0,0};
        for (int n = tid; n < 1552; n += 256) {
            size_t off;
            if (n < 392)       off = (size_t)n * 8;
            else if (n < 784)  off = (size_t)97 * PROW + (size_t)(n - 392) * 8;
            else {
                int m = n - 784;
                int vq = m >> 3, side = (m >> 2) & 1, sub = m & 3;
                off = ((size_t)(vq + 1) * 98 + side * 97) * 32 + sub * 8;
            }
            *(bh8*)&base[off] = z;
        }
        return;
    }
    if (bid < 195) {
        int i = (bid - 192) * 256 + tid;
        if (i < 768) {
            float* o = (float*)(ws + b3_off);
            o[i] = (i < 256) ? bq[i] : (i < 512 ? bk[i - 256] : bv[i - 512]);
        }
        return;
    }
    if (bid < 195 + packBlocks) {
        int n = (bid - 195) * 256 + tid;
        if (n >= pa.start[NPK]) return;
        int s = 0;
#pragma unroll
        for (int k = 1; k < NPK; ++k) if (n >= pa.start[k]) s = k;
        int m   = n - pa.start[s];
        int kl  = m & 31;
        int rem = m >> 5;
        int col = rem % pa.csrc[s]; rem /= pa.csrc[s];
        int tap = rem % pa.taps[s];
        int kc  = rem / pa.taps[s];
        int ci  = kc * 32 + kl;
        int g   = (kl >> 2) & 3;
        int i   = ((kl >> 4) << 2) | (kl & 3);
        int cog = pa.cobase[s] + col;
        int cot = cog >> 4, lc = cog & 15;
        float v = pa.w[s][((size_t)col * pa.cin[s] + ci) * pa.taps[s] + tap];
        if (pa.scale[s]) v *= pa.scale[s][0];
        ws[pa.dst[s] +
           ((((size_t)(pa.kcb[s] + kc) * pa.taps[s] + tap) * pa.cot[s] + cot) * 64
            + (g * 16 + lc)) * 8 + i] = f2bf(v);
        return;
    }

    __shared__ ushort tile[96 * 32];
    int cvb = bid - (195 + packBlocks);
    int v = cvb % 96, kc = (cvb / 96) & 7, b = cvb / 768;
    int ci = tid >> 3, tp = tid & 7;
    const float* src = x + (((size_t)(b * 256 + kc * 32 + ci)) * 96 + v) * 96 + tp * 12;
    int pc = cperm(ci);
    int gci = pc >> 3, idx = pc & 7;
#pragma unroll
    for (int u = 0; u < 12; ++u) {
        int t = tp * 12 + u;
        int sw = ((t + 1) >> 1) & 3;
        tile[t * 32 + 8 * (gci ^ sw) + idx] = f2bf(src[u]);
    }
    __syncthreads();
    ushort* dst = ws + x32_off + (((size_t)(b * 8 + kc) * 98 + v + 1) * 98 + 1) * 32;
    for (int n = tid; n < 384; n += 256)
        *(bh8*)&dst[n * 8] = *(const bh8*)&tile[n * 8];
}

// -------------------------------------------------------------------------
// 2-phase conv (R9-plain body), used for qkv (CT=6) and fused cAttn qkv.
// OMODE: 0 = bf16 planes; 6 = fused cAttn qkv (QKC planes + VCT transposed)
// -------------------------------------------------------------------------
template<int TAPS, int CT, int OMODE, int KU, int NWC>
__global__ __launch_bounds__(512, 2) void conv_mfma(
    const ushort* __restrict__ xin, const ushort* __restrict__ wpk,
    ushort* __restrict__ obf, ushort* __restrict__ aux,
    float* __restrict__ oacc, const float* __restrict__ bias, int KC)
{
    constexpr int ROWS  = (TAPS == 9) ? 3 : 1;
    constexpr int CH1   = (ROWS * PROW * 2 + 1023) / 1024;
    constexpr int CHUNKS = KU * CH1;
    constexpr int BUFSZ = CHUNKS * 512;
    constexpr int COT   = NWC * CT;
    constexpr int COUT  = COT * 16;
    constexpr int NT    = (NWC == 8) ? 6 : 3;
    __shared__ ushort sx[2][BUFSZ];

    const int v0 = blockIdx.x, b = blockIdx.y;
    const int tid = threadIdx.x;
    const int w = tid >> 6, l = tid & 63;
    const int g = l >> 4, lc = l & 15;
    const int wc = w % NWC, sub = w / NWC;
    const int tbase = (NWC == 4) ? sub * 48 : 0;

    f4 acc[CT][NT];
#pragma unroll
    for (int ct = 0; ct < CT; ++ct)
#pragma unroll
        for (int nt = 0; nt < NT; ++nt) acc[ct][nt] = (f4){0.f, 0.f, 0.f, 0.f};

    const bh8* wp0 = (const bh8*)wpk + (size_t)(wc * CT) * 64 + l;

    auto stage = [&](int kcp, int buf) {
#pragma unroll
        for (int u = 0; u < KU; ++u) {
            const ushort* src = xin +
                (((size_t)b * KC + kcp * KU + u) * 98 + v0
                 + ((TAPS == 9) ? 0 : 1)) * (size_t)PROW;
#pragma unroll
            for (int c = 0; c < (CH1 + 7) / 8; ++c) {
                int ch = w + c * 8;
                if (ch < CH1)
                    gld16(src + ch * 512 + l * 8,
                          &sx[buf][(u * CH1 + ch) * 512 + l * 8]);
            }
        }
    };

    stage(0, 0);
    __syncthreads();
    const int NP = KC / KU;
    for (int kcp = 0; kcp < NP; ++kcp) {
        const int cur = kcp & 1;
        if (kcp + 1 < NP) stage(kcp + 1, cur ^ 1);
#pragma unroll
        for (int u = 0; u < KU; ++u) {
            const int kc = kcp * KU + u;
#pragma unroll
            for (int tap = 0; tap < TAPS; ++tap) {
                const int kh = (TAPS == 9) ? tap / 3 : 0;
                const int kw = (TAPS == 9) ? tap % 3 : 1;
                bh8 af[CT];
#pragma unroll
                for (int ct = 0; ct < CT; ++ct)
                    af[ct] = wp0[(((size_t)kc * TAPS + tap) * COT + ct) * 64];
#pragma unroll
                for (int nt = 0; nt < NT; ++nt) {
                    int tp = tbase + nt * 16 + lc + kw;
                    bh8 bf = *(const bh8*)&sx[cur][u * CH1 * 512 + kh * PROW
                                                   + tp * 32
                                                   + 8 * (g ^ ((tp >> 1) & 3))];
#pragma unroll
                    for (int ct = 0; ct < CT; ++ct)
                        acc[ct][nt] = __builtin_amdgcn_mfma_f32_16x16x32_bf16(
                            af[ct], bf, acc[ct][nt], 0, 0, 0);
                }
            }
        }
        __syncthreads();
    }

#pragma unroll
    for (int ct = 0; ct < CT; ++ct) {
#pragma unroll
        for (int nt = 0; nt < NT; ++nt) {
            int tt = tbase + nt * 16 + lc;
            if (OMODE == 0) {
#pragma unroll
                for (int j = 0; j < 4; ++j) {
                    int cog = (wc * CT + ct) * 16 + g * 4 + j;
                    float val = acc[ct][nt][j];
                    if (bias) val += bias[cog];
                    obf[(((size_t)b * COUT + cog) * 96 + v0) * 96 + tt] = f2bf(val);
                }
            } else {
                int cogb = (wc * CT + ct) * 16;
                if (cogb < 512) {
#pragma unroll
                    for (int j = 0; j < 4; ++j) {
                        int cog = cogb + g * 4 + j;
                        float val = acc[ct][nt][j] + bias[cog];
                        obf[(((size_t)b * 512 + cog) * 96 + v0) * 96 + tt] = f2bf(val);
                    }
                } else {
                    bh4 o;
#pragma unroll
                    for (int j = 0; j < 4; ++j)
                        o[j] = (short)f2bf(acc[ct][nt][j] + bias[cogb + g * 4 + j]);
                    *(bh4*)&aux[(((size_t)b * 96 + v0) * 96 + tt) * 256
                                + (cogb - 512) + g * 4] = o;
                }
            }
        }
    }
}

// -------------------------------------------------------------------------
// FINAL conv with weight-one-phase-ahead pipeline. CT=2, NWC=8 (all waves on
// co, NT=6). wfA/wfB double-buffered in registers: phase t's MFMA section has
// ZERO weight waits; W_{t+1} loads issue during phase t and are 1 phase old
// when waited. 3 LDS x-buffers; per-iter raw s_barrier + sched_barrier fence.
// Publish correctness: using W_{t-1} (issued after S(t)) retires S(t) via
// in-order vmcnt before the iter-t barrier -- no manual counts needed.
// out = bf16 residual (xres32, slot-swizzled) + acc  (fp32)
// -------------------------------------------------------------------------
__global__ __launch_bounds__(512) void conv_fin_pipe(
    const ushort* __restrict__ xin, const ushort* __restrict__ wpk,
    const ushort* __restrict__ xres32, float* __restrict__ oacc, int KC)
{
    constexpr int CH1 = 19;
    constexpr int CT  = 2;
    constexpr int COT = 16;
    constexpr int NT  = 6;
    __shared__ ushort sx[3][CH1 * 512];

    const int v0 = blockIdx.x, b = blockIdx.y;
    const int tid = threadIdx.x;
    const int w = tid >> 6, l = tid & 63;
    const int g = l >> 4, lc = l & 15;
    const int wc = w;                       // NWC=8

    f4 acc[CT][NT];
#pragma unroll
    for (int ct = 0; ct < CT; ++ct)
#pragma unroll
        for (int nt = 0; nt < NT; ++nt) acc[ct][nt] = (f4){0.f, 0.f, 0.f, 0.f};

    const bh8* wp0 = (const bh8*)wpk + (size_t)(wc * CT) * 64 + l;

    auto stage = [&](int kc, int buf) {
        const ushort* src = xin + (((size_t)b * KC + kc) * 98 + v0) * (size_t)PROW;
#pragma unroll
        for (int c = 0; c < 3; ++c) {
            int ch = w + c * 8;
            if (ch < CH1)
                gld16(src + ch * 512 + l * 8, &sx[buf][ch * 512 + l * 8]);
        }
    };
    bh8 wfA[9][CT], wfB[9][CT];
    auto ldwA = [&](int kc) {
#pragma unroll
        for (int tap = 0; tap < 9; ++tap)
#pragma unroll
            for (int ct = 0; ct < CT; ++ct)
                wfA[tap][ct] = wp0[(((size_t)kc * 9 + tap) * COT + ct) * 64];
    };
    auto ldwB = [&](int kc) {
#pragma unroll
        for (int tap = 0; tap < 9; ++tap)
#pragma unroll
            for (int ct = 0; ct < CT; ++ct)
                wfB[tap][ct] = wp0[(((size_t)kc * 9 + tap) * COT + ct) * 64];
    };
    auto bodyA = [&](int t) {
        const ushort* bp = sx[t % 3];
#pragma unroll
        for (int tap = 0; tap < 9; ++tap) {
            const int kh = tap / 3, kw = tap % 3;
#pragma unroll
            for (int nt = 0; nt < NT; ++nt) {
                int tp = nt * 16 + lc + kw;
                bh8 bf = *(const bh8*)&bp[kh * PROW + tp * 32
                                          + 8 * (g ^ ((tp >> 1) & 3))];
#pragma unroll
                for (int ct = 0; ct < CT; ++ct)
                    acc[ct][nt] = __builtin_amdgcn_mfma_f32_16x16x32_bf16(
                        wfA[tap][ct], bf, acc[ct][nt], 0, 0, 0);
            }
        }
    };
    auto bodyB = [&](int t) {
        const ushort* bp = sx[t % 3];
#pragma unroll
        for (int tap = 0; tap < 9; ++tap) {
            const int kh = tap / 3, kw = tap % 3;
#pragma unroll
            for (int nt = 0; nt < NT; ++nt) {
                int tp = nt * 16 + lc + kw;
                bh8 bf = *(const bh8*)&bp[kh * PROW + tp * 32
                                          + 8 * (g ^ ((tp >> 1) & 3))];
#pragma unroll
                for (int ct = 0; ct < CT; ++ct)
                    acc[ct][nt] = __builtin_amdgcn_mfma_f32_16x16x32_bf16(
                        wfB[tap][ct], bf, acc[ct][nt], 0, 0, 0);
            }
        }
    };

    stage(0, 0);
    stage(1, 1);
    ldwA(0);
    asm volatile("s_waitcnt vmcnt(0)" ::: "memory");
    __builtin_amdgcn_s_barrier();
    __builtin_amdgcn_sched_barrier(0);

    for (int t = 0; t < KC; t += 2) {
        if (t) {
            __builtin_amdgcn_s_barrier();
            __builtin_amdgcn_sched_barrier(0);
        }
        if (t + 2 < KC) stage(t + 2, (t + 2) % 3);
        if (t + 1 < KC) ldwB(t + 1);
        bodyA(t);
        if (t + 1 < KC) {
            __builtin_amdgcn_s_barrier();
            __builtin_amdgcn_sched_barrier(0);
            if (t + 3 < KC) stage(t + 3, (t + 3) % 3);
            if (t + 2 < KC) ldwA(t + 2);
            bodyB(t + 1);
        }
    }

    // ---- epilogue: out = bf16 residual + acc ----
#pragma unroll
    for (int ct = 0; ct < CT; ++ct) {
#pragma unroll
        for (int nt = 0; nt < NT; ++nt) {
            int tt = nt * 16 + lc;
            int cb  = (wc * CT + ct) * 16 + g * 4;
            int ci5 = cb & 31;
            int gci = (ci5 >> 2) & 3;
            int idx = 4 * (ci5 >> 4);
            int swr = ((1 + tt) >> 1) & 3;
            const ushort* xr = xres32 +
                ((((size_t)b * 8 + (cb >> 5)) * 98 + 1 + v0) * 98 + 1 + tt) * 32;
            bh4 rvv = *(const bh4*)&xr[8 * (gci ^ swr) + idx];
#pragma unroll
            for (int j = 0; j < 4; ++j) {
                size_t o = (((size_t)b * 256 + cb + j) * 96 + v0) * 96 + tt;
                oacc[o] = bf2f((ushort)rvv[j]) + acc[ct][nt][j];
            }
        }
    }
}

// -------------------------------------------------------------------------
__global__ __launch_bounds__(256) void transpose_vt_k(const ushort* __restrict__ in,
                                                      ushort* __restrict__ out,
                                                      int cs_in, int cn)
{
    __shared__ ushort tile[96][100];
    int b = blockIdx.x / cn, c = blockIdx.x % cn;
    size_t sbase = ((size_t)b * cs_in + c) * NVT;
    size_t dbase = (size_t)blockIdx.x * NVT;
    for (int n = threadIdx.x; n < NVT; n += 256) tile[n / 96][n % 96] = in[sbase + n];
    __syncthreads();
    for (int n = threadIdx.x; n < NVT; n += 256) out[dbase + n] = tile[n % 96][n / 96];
}

// -------------------------------------------------------------------------
// vAttn + tAttn in ONE dispatch: blockIdx.y = 0 -> v (qkvA, transposed src),
// 1 -> t (qkvB, native).  av stored into AVALL (slot-swizzled).
// -------------------------------------------------------------------------
__global__ __launch_bounds__(384) void attn_vt_mfma_k(const ushort* __restrict__ qkvA,
                                                      const ushort* __restrict__ qkvB,
                                                      ushort* __restrict__ avall)
{
    __shared__ ushort sQT[96 * 40];
    __shared__ ushort sKT[96 * 40];
    __shared__ ushort sV[128 * 104];

    const bool over_v = (blockIdx.y == 0);
    const ushort* qkv = over_v ? qkvA : qkvB;
    const int cstride = over_v ? 192 : 384;
    const int cbase   = over_v ? 0 : 192;
    const int sec     = over_v ? 0 : 4;

    int b = blockIdx.x / 96, p = blockIdx.x % 96;
    int tid = threadIdx.x;
    int wv = tid >> 6, l = tid & 63;
    int g = l >> 4, lc = l & 15;

    const size_t base = ((size_t)b * cstride + cbase) * (size_t)NVT + (size_t)p * 96;

    for (int s = tid; s < 768; s += 384) {
        int hf = s / 384;
        int c  = (s % 384) / 12;
        int m  = s % 12;
        bh8 val = *(const bh8*)&qkv[base + (size_t)(hf * 32 + c) * NVT + 8 * m];
        ushort* dst = hf ? sKT : sQT;
#pragma unroll
        for (int u = 0; u < 8; ++u)
            dst[(8 * m + u) * 40 + c] = (ushort)val[u];
    }
    for (int s = tid; s < 1536; s += 384) {
        int c = s / 12, m = s % 12;
        *(bh8*)&sV[c * 104 + 8 * m] =
            *(const bh8*)&qkv[base + (size_t)(64 + c) * NVT + 8 * m];
    }
    __syncthreads();

    bh4 qlo = *(const bh4*)&sQT[(wv * 16 + lc) * 40 + 4 * g];
    bh4 qhi = *(const bh4*)&sQT[(wv * 16 + lc) * 40 + 4 * g + 16];
    bh8 bq = __builtin_shufflevector(qlo, qhi, 0, 1, 2, 3, 4, 5, 6, 7);

    f4 st[6];
#pragma unroll
    for (int mt = 0; mt < 6; ++mt) {
        bh4 alo = *(const bh4*)&sKT[(mt * 16 + lc) * 40 + 4 * g];
        bh4 ahi = *(const bh4*)&sKT[(mt * 16 + lc) * 40 + 4 * g + 16];
        bh8 ak = __builtin_shufflevector(alo, ahi, 0, 1, 2, 3, 4, 5, 6, 7);
        st[mt] = __builtin_amdgcn_mfma_f32_16x16x32_bf16(ak, bq,
                                                         (f4){0.f, 0.f, 0.f, 0.f},
                                                         0, 0, 0);
    }

    float mx = -1e30f;
#pragma unroll
    for (int mt = 0; mt < 6; ++mt)
#pragma unroll
        for (int j = 0; j < 4; ++j) mx = fmaxf(mx, st[mt][j]);
    mx = fmaxf(mx, __shfl_xor(mx, 16));
    mx = fmaxf(mx, __shfl_xor(mx, 32));
    float sum = 0.f;
#pragma unroll
    for (int mt = 0; mt < 6; ++mt)
#pragma unroll
        for (int j = 0; j < 4; ++j) {
            float e = __expf(st[mt][j] - mx);
            st[mt][j] = e;
            sum += e;
        }
    sum += __shfl_xor(sum, 16);
    sum += __shfl_xor(sum, 32);
    float inv = 1.f / sum;

    bh8 pf[3];
#pragma unroll
    for (int ks = 0; ks < 3; ++ks) {
        bh8 t;
#pragma unroll
        for (int i = 0; i < 8; ++i)
            t[i] = (short)f2bf(st[2 * ks + (i >> 2)][i & 3] * inv);
        pf[ks] = t;
    }

    f4 acc[8];
#pragma unroll
    for (int mt = 0; mt < 8; ++mt) acc[mt] = (f4){0.f, 0.f, 0.f, 0.f};
#pragma unroll
    for (int ks = 0; ks < 3; ++ks)
#pragma unroll
        for (int mt = 0; mt < 8; ++mt) {
            bh4 alo = *(const bh4*)&sV[(mt * 16 + lc) * 104 + ks * 32 + 4 * g];
            bh4 ahi = *(const bh4*)&sV[(mt * 16 + lc) * 104 + ks * 32 + 4 * g + 16];
            bh8 avf = __builtin_shufflevector(alo, ahi, 0, 1, 2, 3, 4, 5, 6, 7);
            acc[mt] = __builtin_amdgcn_mfma_f32_16x16x32_bf16(avf, pf[ks],
                                                              acc[mt], 0, 0, 0);
        }

    int i = wv * 16 + lc;
#pragma unroll
    for (int mt = 0; mt < 8; ++mt) {
        int vv_ = over_v ? i : p;
        int tt_ = over_v ? p : i;
        int sw  = ((1 + tt_) >> 1) & 3;
        bh4 o;
#pragma unroll
        for (int j = 0; j < 4; ++j) o[j] = (short)f2bf(acc[mt][j]);
        size_t off = ((((size_t)b * 16 + sec + (mt >> 1)) * 98 + 1 + vv_) * 98
                      + 1 + tt_) * 32 + 8 * (g ^ sw) + 4 * (mt & 1);
        *(bh4*)&avall[off] = o;
    }
}

// -------------------------------------------------------------------------
// cAttn via MFMA: q/k from fused QKC [b][512][9216]; av to AVALL (swizzled).
// -------------------------------------------------------------------------
__global__ __launch_bounds__(256) void attn_c_k(const ushort* __restrict__ qkc,
    const ushort* __restrict__ vc, ushort* __restrict__ avall)
{
    __shared__ ushort sQ[64 * 104];
    __shared__ ushort sK[256 * 104];
    __shared__ ushort sV[96 * 264];
    __shared__ ushort sP[64 * 264];

    int v = blockIdx.x, cc = blockIdx.y, b = blockIdx.z;
    int c0 = cc * 64;
    int tid = threadIdx.x;
    int w = tid >> 6, l = tid & 63;
    int g = l >> 4, lc = l & 15;

    for (int s = tid; s < 64 * 12; s += 256) {
        int r = s / 12, sg = s % 12;
        *(bh8*)&sQ[r * 104 + sg * 8] =
            *(const bh8*)&qkc[(((size_t)b * 512 + c0 + r) * 96 + v) * 96 + sg * 8];
    }
    for (int s = tid; s < 256 * 12; s += 256) {
        int r = s / 12, sg = s % 12;
        *(bh8*)&sK[r * 104 + sg * 8] =
            *(const bh8*)&qkc[(((size_t)b * 512 + 256 + r) * 96 + v) * 96 + sg * 8];
    }
    for (int s = tid; s < 96 * 32; s += 256) {
        int r = s / 32, sg = s % 32;
        *(bh8*)&sV[r * 264 + sg * 8] =
            *(const bh8*)&vc[(((size_t)b * 96 + v) * 96 + r) * 256 + sg * 8];
    }
    __syncthreads();

    f4 s16[16];
#pragma unroll
    for (int nt = 0; nt < 16; ++nt) s16[nt] = (f4){0.f, 0.f, 0.f, 0.f};
#pragma unroll
    for (int ks = 0; ks < 3; ++ks) {
        bh4 alo = *(const bh4*)&sQ[(w * 16 + lc) * 104 + ks * 32 + 4 * g];
        bh4 ahi = *(const bh4*)&sQ[(w * 16 + lc) * 104 + ks * 32 + 4 * g + 16];
        bh8 aq = __builtin_shufflevector(alo, ahi, 0, 1, 2, 3, 4, 5, 6, 7);
#pragma unroll
        for (int nt = 0; nt < 16; ++nt) {
            bh4 blo = *(const bh4*)&sK[(nt * 16 + lc) * 104 + ks * 32 + 4 * g];
            bh4 bhi = *(const bh4*)&sK[(nt * 16 + lc) * 104 + ks * 32 + 4 * g + 16];
            bh8 bk = __builtin_shufflevector(blo, bhi, 0, 1, 2, 3, 4, 5, 6, 7);
            s16[nt] = __builtin_amdgcn_mfma_f32_16x16x32_bf16(aq, bk, s16[nt], 0, 0, 0);
        }
    }
#pragma unroll
    for (int j = 0; j < 4; ++j) {
        float m = -1e30f;
#pragma unroll
        for (int nt = 0; nt < 16; ++nt) m = fmaxf(m, s16[nt][j]);
        m = fmaxf(m, __shfl_xor(m, 1));
        m = fmaxf(m, __shfl_xor(m, 2));
        m = fmaxf(m, __shfl_xor(m, 4));
        m = fmaxf(m, __shfl_xor(m, 8));
        float sum = 0.f;
#pragma unroll
        for (int nt = 0; nt < 16; ++nt) {
            float e = __expf(s16[nt][j] - m); s16[nt][j] = e; sum += e;
        }
        sum += __shfl_xor(sum, 1);
        sum += __shfl_xor(sum, 2);
        sum += __shfl_xor(sum, 4);
        sum += __shfl_xor(sum, 8);
        float inv = 1.f / sum;
#pragma unroll
        for (int nt = 0; nt < 16; ++nt)
            sP[(w * 16 + g * 4 + j) * 264 + nt * 16 + lc] = f2bf(s16[nt][j] * inv);
    }
    __syncthreads();

    f4 o6[6];
#pragma unroll
    for (int nt = 0; nt < 6; ++nt) o6[nt] = (f4){0.f, 0.f, 0.f, 0.f};
#pragma unroll
    for (int ks = 0; ks < 8; ++ks) {
        bh4 alo = *(const bh4*)&sP[(w * 16 + lc) * 264 + ks * 32 + 4 * g];
        bh4 ahi = *(const bh4*)&sP[(w * 16 + lc) * 264 + ks * 32 + 4 * g + 16];
        bh8 ap = __builtin_shufflevector(alo, ahi, 0, 1, 2, 3, 4, 5, 6, 7);
#pragma unroll
        for (int nt = 0; nt < 6; ++nt) {
            bh4 blo = *(const bh4*)&sV[(nt * 16 + lc) * 264 + ks * 32 + 4 * g];
            bh4 bhi = *(const bh4*)&sV[(nt * 16 + lc) * 264 + ks * 32 + 4 * g + 16];
            bh8 bv = __builtin_shufflevector(blo, bhi, 0, 1, 2, 3, 4, 5, 6, 7);
            o6[nt] = __builtin_amdgcn_mfma_f32_16x16x32_bf16(ap, bv, o6[nt], 0, 0, 0);
        }
    }
#pragma unroll
    for (int nt = 0; nt < 6; ++nt) {
        int t = nt * 16 + lc;
        int sw = ((1 + t) >> 1) & 3;
        bh4 o;
#pragma unroll
        for (int j = 0; j < 4; ++j) o[j] = (short)f2bf(o6[nt][j]);
        size_t off = ((((size_t)b * 16 + 8 + cc * 2 + (w >> 1)) * 98 + 1 + v) * 98
                      + 1 + t) * 32 + 8 * (g ^ sw) + 4 * (w & 1);
        *(bh4*)&avall[off] = o;
    }
}

// -------------------------------------------------------------------------
extern "C" void kernel_launch(void* const* d_in, const int* in_sizes, int n_in,
                              void* d_out, int out_size, void* d_ws, size_t ws_size,
                              hipStream_t stream)
{
    const float* x     = (const float*)d_in[0];
    const float* v_wq  = (const float*)d_in[1];
    const float* v_wk  = (const float*)d_in[2];
    const float* v_wv  = (const float*)d_in[3];
    const float* v_wo  = (const float*)d_in[4];
    const float* v_sig = (const float*)d_in[5];
    const float* t_wq  = (const float*)d_in[6];
    const float* t_wk  = (const float*)d_in[7];
    const float* t_wv  = (const float*)d_in[8];
    const float* t_wo  = (const float*)d_in[9];
    const float* t_sig = (const float*)d_in[10];
    const float* c_wq  = (const float*)d_in[11];
    const float* c_bq  = (const float*)d_in[12];
    const float* c_wk  = (const float*)d_in[13];
    const float* c_bk  = (const float*)d_in[14];
    const float* c_wv  = (const float*)d_in[15];
    const float* c_bv  = (const float*)d_in[16];
    const float* c_wo  = (const float*)d_in[17];
    const float* c_sig = (const float*)d_in[18];

    float*  out = (float*)d_out;
    ushort* ws  = (ushort*)d_ws;

    const size_t X32  = 0;
    const size_t AVL  = X32 + 19685376;
    const size_t POOL = AVL + 39354368;
    const size_t QKV   = POOL;
    const size_t QKVVT = POOL + 28311552;
    const size_t QKC   = POOL;
    const size_t VCT   = POOL + 37748736;
    const size_t PK    = POOL + 56623104;
    const size_t PK_PVT = PK;
    const size_t PK_C3  = PK_PVT + 884736;
    const size_t PK_FIN = PK_C3 + 196608;
    const size_t B3     = PK_FIN + 1179648;

    PackArgs pa;
    auto setp = [&](int s, const float* w, size_t dst, int cin, int taps,
                    int csrc, int cobase, int cot, int kcb, const float* sc) {
        pa.w[s] = w; pa.scale[s] = sc; pa.dst[s] = (unsigned)dst;
        pa.cin[s] = cin; pa.taps[s] = taps; pa.csrc[s] = csrc;
        pa.cobase[s] = cobase; pa.cot[s] = cot; pa.kcb[s] = kcb;
    };
    setp(0,  v_wq, PK_PVT, 256, 9, 32, 0, 24, 0, nullptr);
    setp(1,  v_wk, PK_PVT, 256, 9, 32, 32, 24, 0, nullptr);
    setp(2,  v_wv, PK_PVT, 256, 9, 128, 64, 24, 0, nullptr);
    setp(3,  t_wq, PK_PVT, 256, 9, 32, 192, 24, 0, nullptr);
    setp(4,  t_wk, PK_PVT, 256, 9, 32, 224, 24, 0, nullptr);
    setp(5,  t_wv, PK_PVT, 256, 9, 128, 256, 24, 0, nullptr);
    setp(6,  c_wq, PK_C3, 256, 1, 256, 0, 48, 0, nullptr);
    setp(7,  c_wk, PK_C3, 256, 1, 256, 256, 48, 0, nullptr);
    setp(8,  c_wv, PK_C3, 256, 1, 256, 512, 48, 0, nullptr);
    setp(9,  v_wo, PK_FIN, 128, 9, 256, 0, 16, 0, v_sig);
    setp(10, t_wo, PK_FIN, 128, 9, 256, 0, 16, 4, t_sig);
    setp(11, c_wo, PK_FIN, 256, 9, 256, 0, 16, 8, c_sig);
    pa.start[0] = 0;
    for (int s = 0; s < NPK; ++s)
        pa.start[s + 1] = pa.start[s]
            + (pa.cin[s] >> 5) * pa.taps[s] * pa.csrc[s] * 32;
    const int packBlocks = (pa.start[NPK] + 255) / 256;
    const int totalBlocks = 195 + packBlocks + 96 * 8 * BB;
    prep_all_k<<<totalBlocks, 256, 0, stream>>>(pa, ws, x,
        (unsigned)X32, (unsigned)AVL, (unsigned)B3, c_bq, c_bk, c_bv, packBlocks);

    // ---- fused v+t qkv projection (COUT=384, CT=6, KU=2, 2-phase) ----
    conv_mfma<9, 6, 0, 2, 4><<<dim3(96, BB), 512, 0, stream>>>(
        ws + X32, ws + PK_PVT, ws + QKV, nullptr, nullptr, nullptr, 8);

    // ---- vAttn + tAttn (transpose, then one merged attention dispatch) ----
    transpose_vt_k<<<BB * 192, 256, 0, stream>>>(ws + QKV, ws + QKVVT, 384, 192);
    attn_vt_mfma_k<<<dim3(BB * 96, 2), 384, 0, stream>>>(ws + QKVVT, ws + QKV,
                                                         ws + AVL);

    // ---- cAttn: ONE fused 1x1 conv (q|k|v), KU=4 ----
    conv_mfma<1, 6, 6, 4, 8><<<dim3(96, BB), 512, 0, stream>>>(
        ws + X32, ws + PK_C3, ws + QKC, ws + VCT, nullptr,
        (const float*)(ws + B3), 8);
    attn_c_k<<<dim3(96, 4, BB), 256, 0, stream>>>(ws + QKC, ws + VCT, ws + AVL);

    // ---- final conv: weight-ahead pipeline + residual ----
    conv_fin_pipe<<<dim3(96, BB), 512, 0, stream>>>(
        ws + AVL, ws + PK_FIN, ws + X32, out, 16);
}

// Round 19
// 582.166 us; speedup vs baseline: 1.0918x; 1.0918x over previous
//
#include <hip/hip_runtime.h>
#include <math.h>

#define BB  8
#define CH  256
#define NVT 9216        // 96*96
#define PLN (98*98*32)  // padded NC32 plane: 307328 shorts
#define PROW (98*32)    // padded row: 3136 shorts
#define NPK 12

typedef short bh8 __attribute__((ext_vector_type(8)));
typedef short bh4 __attribute__((ext_vector_type(4)));
typedef float f4  __attribute__((ext_vector_type(4)));

__device__ __forceinline__ float bf2f(ushort u) {
    union { uint i; float f; } x; x.i = ((uint)u) << 16; return x.f;
}
__device__ __forceinline__ ushort f2bf(float f) {
    union { float f; uint i; } x; x.f = f;
    uint r = (x.i + 0x7FFFu + ((x.i >> 16) & 1u)) >> 16;
    return (ushort)r;
}
__device__ __forceinline__ int cperm(int ci) {
    return 8 * ((ci >> 2) & 3) + 4 * (ci >> 4) + (ci & 3);
}
__device__ __forceinline__ void gld16(const void* g, void* l) {
    __builtin_amdgcn_global_load_lds(
        (const __attribute__((address_space(1))) void*)g,
        (__attribute__((address_space(3))) void*)l, 16, 0, 0);
}

// -------------------------------------------------------------------------
struct PackArgs {
    const float* w[NPK];
    const float* scale[NPK];
    unsigned dst[NPK];
    int cin[NPK], taps[NPK], csrc[NPK], cobase[NPK], cot[NPK], kcb[NPK];
    int start[NPK + 1];
};

// -------------------------------------------------------------------------
// ONE prep dispatch: pads + bias concat + 12 weight packs + x conversion
// -------------------------------------------------------------------------
__global__ __launch_bounds__(256) void prep_all_k(PackArgs pa,
    ushort* __restrict__ ws, const float* __restrict__ x,
    unsigned x32_off, unsigned avl_off, unsigned b3_off,
    const float* __restrict__ bq, const float* __restrict__ bk,
    const float* __restrict__ bv, int packBlocks)
{
    const int bid = blockIdx.x;
    const int tid = threadIdx.x;

    if (bid < 192) {
        int p = bid;
        ushort* base = (p < 64) ? ws + x32_off + (size_t)p * PLN
                                : ws + avl_off + (size_t)(p - 64) * PLN;
        const bh8 z = {0,0,0,0,0,0,0,0};
        for (int n = tid; n < 1552; n += 256) {
            size_t off;
            if (n < 392)       off = (size_t)n * 8;
            else if (n < 784)  off = (size_t)97 * PROW + (size_t)(n - 392) * 8;
            else {
                int m = n - 784;
                int vq = m >> 3, side = (m >> 2) & 1, sub = m & 3;
                off = ((size_t)(vq + 1) * 98 + side * 97) * 32 + sub * 8;
            }
            *(bh8*)&base[off] = z;
        }
        return;
    }
    if (bid < 195) {
        int i = (bid - 192) * 256 + tid;
        if (i < 768) {
            float* o = (float*)(ws + b3_off);
            o[i] = (i < 256) ? bq[i] : (i < 512 ? bk[i - 256] : bv[i - 512]);
        }
        return;
    }
    if (bid < 195 + packBlocks) {
        int n = (bid - 195) * 256 + tid;
        if (n >= pa.start[NPK]) return;
        int s = 0;
#pragma unroll
        for (int k = 1; k < NPK; ++k) if (n >= pa.start[k]) s = k;
        int m   = n - pa.start[s];
        int kl  = m & 31;
        int rem = m >> 5;
        int col = rem % pa.csrc[s]; rem /= pa.csrc[s];
        int tap = rem % pa.taps[s];
        int kc  = rem / pa.taps[s];
        int ci  = kc * 32 + kl;
        int g   = (kl >> 2) & 3;
        int i   = ((kl >> 4) << 2) | (kl & 3);
        int cog = pa.cobase[s] + col;
        int cot = cog >> 4, lc = cog & 15;
        float v = pa.w[s][((size_t)col * pa.cin[s] + ci) * pa.taps[s] + tap];
        if (pa.scale[s]) v *= pa.scale[s][0];
        ws[pa.dst[s] +
           ((((size_t)(pa.kcb[s] + kc) * pa.taps[s] + tap) * pa.cot[s] + cot) * 64
            + (g * 16 + lc)) * 8 + i] = f2bf(v);
        return;
    }

    __shared__ ushort tile[96 * 32];
    int cvb = bid - (195 + packBlocks);
    int v = cvb % 96, kc = (cvb / 96) & 7, b = cvb / 768;
    int ci = tid >> 3, tp = tid & 7;
    const float* src = x + (((size_t)(b * 256 + kc * 32 + ci)) * 96 + v) * 96 + tp * 12;
    int pc = cperm(ci);
    int gci = pc >> 3, idx = pc & 7;
#pragma unroll
    for (int u = 0; u < 12; ++u) {
        int t = tp * 12 + u;
        int sw = ((t + 1) >> 1) & 3;
        tile[t * 32 + 8 * (gci ^ sw) + idx] = f2bf(src[u]);
    }
    __syncthreads();
    ushort* dst = ws + x32_off + (((size_t)(b * 8 + kc) * 98 + v + 1) * 98 + 1) * 32;
    for (int n = tid; n < 384; n += 256)
        *(bh8*)&dst[n * 8] = *(const bh8*)&tile[n * 8];
}

// -------------------------------------------------------------------------
// Proven 2-phase conv (R9-plain schedule). KU = kc-planes per phase.
// NWC=4: waves split co(4) x t-half(2), NT=3.  NWC=8: all waves on co, NT=6.
// OMODE: 0 = bf16 NCHW-compact planes
//        5 = fp32 out = bf16 residual (aux = x32, slot-swizzled) + acc
//        6 = fused cAttn qkv: cog<512 -> QKC planes, cog>=512 -> VCT (aux)
// -------------------------------------------------------------------------
template<int TAPS, int CT, int OMODE, int KU, int NWC>
__global__ __launch_bounds__(512, 2) void conv_mfma(
    const ushort* __restrict__ xin, const ushort* __restrict__ wpk,
    ushort* __restrict__ obf, ushort* __restrict__ aux,
    float* __restrict__ oacc, const float* __restrict__ bias, int KC)
{
    constexpr int ROWS  = (TAPS == 9) ? 3 : 1;
    constexpr int CH1   = (ROWS * PROW * 2 + 1023) / 1024;
    constexpr int CHUNKS = KU * CH1;
    constexpr int BUFSZ = CHUNKS * 512;
    constexpr int COT   = NWC * CT;
    constexpr int COUT  = COT * 16;
    constexpr int NT    = (NWC == 8) ? 6 : 3;
    __shared__ ushort sx[2][BUFSZ];

    const int v0 = blockIdx.x, b = blockIdx.y;
    const int tid = threadIdx.x;
    const int w = tid >> 6, l = tid & 63;
    const int g = l >> 4, lc = l & 15;
    const int wc = w % NWC, sub = w / NWC;
    const int tbase = (NWC == 4) ? sub * 48 : 0;

    f4 acc[CT][NT];
#pragma unroll
    for (int ct = 0; ct < CT; ++ct)
#pragma unroll
        for (int nt = 0; nt < NT; ++nt) acc[ct][nt] = (f4){0.f, 0.f, 0.f, 0.f};

    const bh8* wp0 = (const bh8*)wpk + (size_t)(wc * CT) * 64 + l;

    auto stage = [&](int kcp, int buf) {
#pragma unroll
        for (int u = 0; u < KU; ++u) {
            const ushort* src = xin +
                (((size_t)b * KC + kcp * KU + u) * 98 + v0
                 + ((TAPS == 9) ? 0 : 1)) * (size_t)PROW;
#pragma unroll
            for (int c = 0; c < (CH1 + 7) / 8; ++c) {
                int ch = w + c * 8;
                if (ch < CH1)
                    gld16(src + ch * 512 + l * 8,
                          &sx[buf][(u * CH1 + ch) * 512 + l * 8]);
            }
        }
    };

    stage(0, 0);
    __syncthreads();
    const int NP = KC / KU;
    for (int kcp = 0; kcp < NP; ++kcp) {
        const int cur = kcp & 1;
        if (kcp + 1 < NP) stage(kcp + 1, cur ^ 1);
#pragma unroll
        for (int u = 0; u < KU; ++u) {
            const int kc = kcp * KU + u;
#pragma unroll
            for (int tap = 0; tap < TAPS; ++tap) {
                const int kh = (TAPS == 9) ? tap / 3 : 0;
                const int kw = (TAPS == 9) ? tap % 3 : 1;
                bh8 af[CT];
#pragma unroll
                for (int ct = 0; ct < CT; ++ct)
                    af[ct] = wp0[(((size_t)kc * TAPS + tap) * COT + ct) * 64];
#pragma unroll
                for (int nt = 0; nt < NT; ++nt) {
                    int tp = tbase + nt * 16 + lc + kw;
                    bh8 bf = *(const bh8*)&sx[cur][u * CH1 * 512 + kh * PROW
                                                   + tp * 32
                                                   + 8 * (g ^ ((tp >> 1) & 3))];
#pragma unroll
                    for (int ct = 0; ct < CT; ++ct)
                        acc[ct][nt] = __builtin_amdgcn_mfma_f32_16x16x32_bf16(
                            af[ct], bf, acc[ct][nt], 0, 0, 0);
                }
            }
        }
        __syncthreads();
    }

#pragma unroll
    for (int ct = 0; ct < CT; ++ct) {
#pragma unroll
        for (int nt = 0; nt < NT; ++nt) {
            int tt = tbase + nt * 16 + lc;
            if (OMODE == 0) {
#pragma unroll
                for (int j = 0; j < 4; ++j) {
                    int cog = (wc * CT + ct) * 16 + g * 4 + j;
                    float val = acc[ct][nt][j];
                    if (bias) val += bias[cog];
                    obf[(((size_t)b * COUT + cog) * 96 + v0) * 96 + tt] = f2bf(val);
                }
            } else if (OMODE == 6) {
                int cogb = (wc * CT + ct) * 16;
                if (cogb < 512) {
#pragma unroll
                    for (int j = 0; j < 4; ++j) {
                        int cog = cogb + g * 4 + j;
                        float val = acc[ct][nt][j] + bias[cog];
                        obf[(((size_t)b * 512 + cog) * 96 + v0) * 96 + tt] = f2bf(val);
                    }
                } else {
                    bh4 o;
#pragma unroll
                    for (int j = 0; j < 4; ++j)
                        o[j] = (short)f2bf(acc[ct][nt][j] + bias[cogb + g * 4 + j]);
                    *(bh4*)&aux[(((size_t)b * 96 + v0) * 96 + tt) * 256
                                + (cogb - 512) + g * 4] = o;
                }
            } else {
                int cb  = (wc * CT + ct) * 16 + g * 4;
                int ci5 = cb & 31;
                int gci = (ci5 >> 2) & 3;
                int idx = 4 * (ci5 >> 4);
                int swr = ((1 + tt) >> 1) & 3;
                const ushort* xr = (const ushort*)aux +
                    ((((size_t)b * 8 + (cb >> 5)) * 98 + 1 + v0) * 98 + 1 + tt) * 32;
                bh4 rvv = *(const bh4*)&xr[8 * (gci ^ swr) + idx];
#pragma unroll
                for (int j = 0; j < 4; ++j) {
                    size_t o = (((size_t)b * 256 + cb + j) * 96 + v0) * 96 + tt;
                    oacc[o] = bf2f((ushort)rvv[j]) + acc[ct][nt][j];
                }
            }
        }
    }
}

// -------------------------------------------------------------------------
__global__ __launch_bounds__(256) void transpose_vt_k(const ushort* __restrict__ in,
                                                      ushort* __restrict__ out,
                                                      int cs_in, int cn)
{
    __shared__ ushort tile[96][100];
    int b = blockIdx.x / cn, c = blockIdx.x % cn;
    size_t sbase = ((size_t)b * cs_in + c) * NVT;
    size_t dbase = (size_t)blockIdx.x * NVT;
    for (int n = threadIdx.x; n < NVT; n += 256) tile[n / 96][n % 96] = in[sbase + n];
    __syncthreads();
    for (int n = threadIdx.x; n < NVT; n += 256) out[dbase + n] = tile[n % 96][n / 96];
}

// -------------------------------------------------------------------------
// vAttn + tAttn in ONE dispatch (blockIdx.y selects branch); av -> AVALL.
// -------------------------------------------------------------------------
__global__ __launch_bounds__(384) void attn_vt_mfma_k(const ushort* __restrict__ qkvA,
                                                      const ushort* __restrict__ qkvB,
                                                      ushort* __restrict__ avall)
{
    __shared__ ushort sQT[96 * 40];
    __shared__ ushort sKT[96 * 40];
    __shared__ ushort sV[128 * 104];

    const bool over_v = (blockIdx.y == 0);
    const ushort* qkv = over_v ? qkvA : qkvB;
    const int cstride = over_v ? 192 : 384;
    const int cbase   = over_v ? 0 : 192;
    const int sec     = over_v ? 0 : 4;

    int b = blockIdx.x / 96, p = blockIdx.x % 96;
    int tid = threadIdx.x;
    int wv = tid >> 6, l = tid & 63;
    int g = l >> 4, lc = l & 15;

    const size_t base = ((size_t)b * cstride + cbase) * (size_t)NVT + (size_t)p * 96;

    for (int s = tid; s < 768; s += 384) {
        int hf = s / 384;
        int c  = (s % 384) / 12;
        int m  = s % 12;
        bh8 val = *(const bh8*)&qkv[base + (size_t)(hf * 32 + c) * NVT + 8 * m];
        ushort* dst = hf ? sKT : sQT;
#pragma unroll
        for (int u = 0; u < 8; ++u)
            dst[(8 * m + u) * 40 + c] = (ushort)val[u];
    }
    for (int s = tid; s < 1536; s += 384) {
        int c = s / 12, m = s % 12;
        *(bh8*)&sV[c * 104 + 8 * m] =
            *(const bh8*)&qkv[base + (size_t)(64 + c) * NVT + 8 * m];
    }
    __syncthreads();

    bh4 qlo = *(const bh4*)&sQT[(wv * 16 + lc) * 40 + 4 * g];
    bh4 qhi = *(const bh4*)&sQT[(wv * 16 + lc) * 40 + 4 * g + 16];
    bh8 bq = __builtin_shufflevector(qlo, qhi, 0, 1, 2, 3, 4, 5, 6, 7);

    f4 st[6];
#pragma unroll
    for (int mt = 0; mt < 6; ++mt) {
        bh4 alo = *(const bh4*)&sKT[(mt * 16 + lc) * 40 + 4 * g];
        bh4 ahi = *(const bh4*)&sKT[(mt * 16 + lc) * 40 + 4 * g + 16];
        bh8 ak = __builtin_shufflevector(alo, ahi, 0, 1, 2, 3, 4, 5, 6, 7);
        st[mt] = __builtin_amdgcn_mfma_f32_16x16x32_bf16(ak, bq,
                                                         (f4){0.f, 0.f, 0.f, 0.f},
                                                         0, 0, 0);
    }

    float mx = -1e30f;
#pragma unroll
    for (int mt = 0; mt < 6; ++mt)
#pragma unroll
        for (int j = 0; j < 4; ++j) mx = fmaxf(mx, st[mt][j]);
    mx = fmaxf(mx, __shfl_xor(mx, 16));
    mx = fmaxf(mx, __shfl_xor(mx, 32));
    float sum = 0.f;
#pragma unroll
    for (int mt = 0; mt < 6; ++mt)
#pragma unroll
        for (int j = 0; j < 4; ++j) {
            float e = __expf(st[mt][j] - mx);
            st[mt][j] = e;
            sum += e;
        }
    sum += __shfl_xor(sum, 16);
    sum += __shfl_xor(sum, 32);
    float inv = 1.f / sum;

    bh8 pf[3];
#pragma unroll
    for (int ks = 0; ks < 3; ++ks) {
        bh8 t;
#pragma unroll
        for (int i = 0; i < 8; ++i)
            t[i] = (short)f2bf(st[2 * ks + (i >> 2)][i & 3] * inv);
        pf[ks] = t;
    }

    f4 acc[8];
#pragma unroll
    for (int mt = 0; mt < 8; ++mt) acc[mt] = (f4){0.f, 0.f, 0.f, 0.f};
#pragma unroll
    for (int ks = 0; ks < 3; ++ks)
#pragma unroll
        for (int mt = 0; mt < 8; ++mt) {
            bh4 alo = *(const bh4*)&sV[(mt * 16 + lc) * 104 + ks * 32 + 4 * g];
            bh4 ahi = *(const bh4*)&sV[(mt * 16 + lc) * 104 + ks * 32 + 4 * g + 16];
            bh8 avf = __builtin_shufflevector(alo, ahi, 0, 1, 2, 3, 4, 5, 6, 7);
            acc[mt] = __builtin_amdgcn_mfma_f32_16x16x32_bf16(avf, pf[ks],
                                                              acc[mt], 0, 0, 0);
        }

    int i = wv * 16 + lc;
#pragma unroll
    for (int mt = 0; mt < 8; ++mt) {
        int vv_ = over_v ? i : p;
        int tt_ = over_v ? p : i;
        int sw  = ((1 + tt_) >> 1) & 3;
        bh4 o;
#pragma unroll
        for (int j = 0; j < 4; ++j) o[j] = (short)f2bf(acc[mt][j]);
        size_t off = ((((size_t)b * 16 + sec + (mt >> 1)) * 98 + 1 + vv_) * 98
                      + 1 + tt_) * 32 + 8 * (g ^ sw) + 4 * (mt & 1);
        *(bh4*)&avall[off] = o;
    }
}

// -------------------------------------------------------------------------
// cAttn via MFMA: q/k from fused QKC [b][512][9216]; av to AVALL (swizzled).
// -------------------------------------------------------------------------
__global__ __launch_bounds__(256) void attn_c_k(const ushort* __restrict__ qkc,
    const ushort* __restrict__ vc, ushort* __restrict__ avall)
{
    __shared__ ushort sQ[64 * 104];
    __shared__ ushort sK[256 * 104];
    __shared__ ushort sV[96 * 264];
    __shared__ ushort sP[64 * 264];

    int v = blockIdx.x, cc = blockIdx.y, b = blockIdx.z;
    int c0 = cc * 64;
    int tid = threadIdx.x;
    int w = tid >> 6, l = tid & 63;
    int g = l >> 4, lc = l & 15;

    for (int s = tid; s < 64 * 12; s += 256) {
        int r = s / 12, sg = s % 12;
        *(bh8*)&sQ[r * 104 + sg * 8] =
            *(const bh8*)&qkc[(((size_t)b * 512 + c0 + r) * 96 + v) * 96 + sg * 8];
    }
    for (int s = tid; s < 256 * 12; s += 256) {
        int r = s / 12, sg = s % 12;
        *(bh8*)&sK[r * 104 + sg * 8] =
            *(const bh8*)&qkc[(((size_t)b * 512 + 256 + r) * 96 + v) * 96 + sg * 8];
    }
    for (int s = tid; s < 96 * 32; s += 256) {
        int r = s / 32, sg = s % 32;
        *(bh8*)&sV[r * 264 + sg * 8] =
            *(const bh8*)&vc[(((size_t)b * 96 + v) * 96 + r) * 256 + sg * 8];
    }
    __syncthreads();

    f4 s16[16];
#pragma unroll
    for (int nt = 0; nt < 16; ++nt) s16[nt] = (f4){0.f, 0.f, 0.f, 0.f};
#pragma unroll
    for (int ks = 0; ks < 3; ++ks) {
        bh4 alo = *(const bh4*)&sQ[(w * 16 + lc) * 104 + ks * 32 + 4 * g];
        bh4 ahi = *(const bh4*)&sQ[(w * 16 + lc) * 104 + ks * 32 + 4 * g + 16];
        bh8 aq = __builtin_shufflevector(alo, ahi, 0, 1, 2, 3, 4, 5, 6, 7);
#pragma unroll
        for (int nt = 0; nt < 16; ++nt) {
            bh4 blo = *(const bh4*)&sK[(nt * 16 + lc) * 104 + ks * 32 + 4 * g];
            bh4 bhi = *(const bh4*)&sK[(nt * 16 + lc) * 104 + ks * 32 + 4 * g + 16];
            bh8 bk = __builtin_shufflevector(blo, bhi, 0, 1, 2, 3, 4, 5, 6, 7);
            s16[nt] = __builtin_amdgcn_mfma_f32_16x16x32_bf16(aq, bk, s16[nt], 0, 0, 0);
        }
    }
#pragma unroll
    for (int j = 0; j < 4; ++j) {
        float m = -1e30f;
#pragma unroll
        for (int nt = 0; nt < 16; ++nt) m = fmaxf(m, s16[nt][j]);
        m = fmaxf(m, __shfl_xor(m, 1));
        m = fmaxf(m, __shfl_xor(m, 2));
        m = fmaxf(m, __shfl_xor(m, 4));
        m = fmaxf(m, __shfl_xor(m, 8));
        float sum = 0.f;
#pragma unroll
        for (int nt = 0; nt < 16; ++nt) {
            float e = __expf(s16[nt][j] - m); s16[nt][j] = e; sum += e;
        }
        sum += __shfl_xor(sum, 1);
        sum += __shfl_xor(sum, 2);
        sum += __shfl_xor(sum, 4);
        sum += __shfl_xor(sum, 8);
        float inv = 1.f / sum;
#pragma unroll
        for (int nt = 0; nt < 16; ++nt)
            sP[(w * 16 + g * 4 + j) * 264 + nt * 16 + lc] = f2bf(s16[nt][j] * inv);
    }
    __syncthreads();

    f4 o6[6];
#pragma unroll
    for (int nt = 0; nt < 6; ++nt) o6[nt] = (f4){0.f, 0.f, 0.f, 0.f};
#pragma unroll
    for (int ks = 0; ks < 8; ++ks) {
        bh4 alo = *(const bh4*)&sP[(w * 16 + lc) * 264 + ks * 32 + 4 * g];
        bh4 ahi = *(const bh4*)&sP[(w * 16 + lc) * 264 + ks * 32 + 4 * g + 16];
        bh8 ap = __builtin_shufflevector(alo, ahi, 0, 1, 2, 3, 4, 5, 6, 7);
#pragma unroll
        for (int nt = 0; nt < 6; ++nt) {
            bh4 blo = *(const bh4*)&sV[(nt * 16 + lc) * 264 + ks * 32 + 4 * g];
            bh4 bhi = *(const bh4*)&sV[(nt * 16 + lc) * 264 + ks * 32 + 4 * g + 16];
            bh8 bv = __builtin_shufflevector(blo, bhi, 0, 1, 2, 3, 4, 5, 6, 7);
            o6[nt] = __builtin_amdgcn_mfma_f32_16x16x32_bf16(ap, bv, o6[nt], 0, 0, 0);
        }
    }
#pragma unroll
    for (int nt = 0; nt < 6; ++nt) {
        int t = nt * 16 + lc;
        int sw = ((1 + t) >> 1) & 3;
        bh4 o;
#pragma unroll
        for (int j = 0; j < 4; ++j) o[j] = (short)f2bf(o6[nt][j]);
        size_t off = ((((size_t)b * 16 + 8 + cc * 2 + (w >> 1)) * 98 + 1 + v) * 98
                      + 1 + t) * 32 + 8 * (g ^ sw) + 4 * (w & 1);
        *(bh4*)&avall[off] = o;
    }
}

// -------------------------------------------------------------------------
extern "C" void kernel_launch(void* const* d_in, const int* in_sizes, int n_in,
                              void* d_out, int out_size, void* d_ws, size_t ws_size,
                              hipStream_t stream)
{
    const float* x     = (const float*)d_in[0];
    const float* v_wq  = (const float*)d_in[1];
    const float* v_wk  = (const float*)d_in[2];
    const float* v_wv  = (const float*)d_in[3];
    const float* v_wo  = (const float*)d_in[4];
    const float* v_sig = (const float*)d_in[5];
    const float* t_wq  = (const float*)d_in[6];
    const float* t_wk  = (const float*)d_in[7];
    const float* t_wv  = (const float*)d_in[8];
    const float* t_wo  = (const float*)d_in[9];
    const float* t_sig = (const float*)d_in[10];
    const float* c_wq  = (const float*)d_in[11];
    const float* c_bq  = (const float*)d_in[12];
    const float* c_wk  = (const float*)d_in[13];
    const float* c_bk  = (const float*)d_in[14];
    const float* c_wv  = (const float*)d_in[15];
    const float* c_bv  = (const float*)d_in[16];
    const float* c_wo  = (const float*)d_in[17];
    const float* c_sig = (const float*)d_in[18];

    float*  out = (float*)d_out;
    ushort* ws  = (ushort*)d_ws;

    // ---- workspace layout (ushort units) -- exact R15 layout ----
    const size_t X32  = 0;                          // [8][8][98][98][32]
    const size_t AVL  = X32 + 19685376;             // [8][16][98][98][32]
    const size_t POOL = AVL + 39354368;
    const size_t QKV   = POOL;                      // [8][384][9216]
    const size_t QKVVT = POOL + 28311552;           // [8][192][9216]
    const size_t QKC   = POOL;                      // [8][512][9216] (alias,
                                                    //  safe: written AFTER
                                                    //  vt attention reads QKV)
    const size_t VCT   = POOL + 37748736;           // [8][96][96][256]
    const size_t PK    = POOL + 56623104;
    const size_t PK_PVT = PK;                       // 884736
    const size_t PK_C3  = PK_PVT + 884736;          // 196608
    const size_t PK_FIN = PK_C3 + 196608;           // 1179648
    const size_t B3     = PK_FIN + 1179648;

    PackArgs pa;
    auto setp = [&](int s, const float* w, size_t dst, int cin, int taps,
                    int csrc, int cobase, int cot, int kcb, const float* sc) {
        pa.w[s] = w; pa.scale[s] = sc; pa.dst[s] = (unsigned)dst;
        pa.cin[s] = cin; pa.taps[s] = taps; pa.csrc[s] = csrc;
        pa.cobase[s] = cobase; pa.cot[s] = cot; pa.kcb[s] = kcb;
    };
    setp(0,  v_wq, PK_PVT, 256, 9, 32, 0, 24, 0, nullptr);
    setp(1,  v_wk, PK_PVT, 256, 9, 32, 32, 24, 0, nullptr);
    setp(2,  v_wv, PK_PVT, 256, 9, 128, 64, 24, 0, nullptr);
    setp(3,  t_wq, PK_PVT, 256, 9, 32, 192, 24, 0, nullptr);
    setp(4,  t_wk, PK_PVT, 256, 9, 32, 224, 24, 0, nullptr);
    setp(5,  t_wv, PK_PVT, 256, 9, 128, 256, 24, 0, nullptr);
    setp(6,  c_wq, PK_C3, 256, 1, 256, 0, 48, 0, nullptr);
    setp(7,  c_wk, PK_C3, 256, 1, 256, 256, 48, 0, nullptr);
    setp(8,  c_wv, PK_C3, 256, 1, 256, 512, 48, 0, nullptr);
    setp(9,  v_wo, PK_FIN, 128, 9, 256, 0, 16, 0, v_sig);
    setp(10, t_wo, PK_FIN, 128, 9, 256, 0, 16, 4, t_sig);
    setp(11, c_wo, PK_FIN, 256, 9, 256, 0, 16, 8, c_sig);
    pa.start[0] = 0;
    for (int s = 0; s < NPK; ++s)
        pa.start[s + 1] = pa.start[s]
            + (pa.cin[s] >> 5) * pa.taps[s] * pa.csrc[s] * 32;
    const int packBlocks = (pa.start[NPK] + 255) / 256;
    const int totalBlocks = 195 + packBlocks + 96 * 8 * BB;
    prep_all_k<<<totalBlocks, 256, 0, stream>>>(pa, ws, x,
        (unsigned)X32, (unsigned)AVL, (unsigned)B3, c_bq, c_bk, c_bv, packBlocks);

    // ---- fused v+t qkv projection (COUT=384, CT=6, KU=2, 2-phase) ----
    conv_mfma<9, 6, 0, 2, 4><<<dim3(96, BB), 512, 0, stream>>>(
        ws + X32, ws + PK_PVT, ws + QKV, nullptr, nullptr, nullptr, 8);

    // ---- vAttn + tAttn (transpose, then one merged attention dispatch) ----
    transpose_vt_k<<<BB * 192, 256, 0, stream>>>(ws + QKV, ws + QKVVT, 384, 192);
    attn_vt_mfma_k<<<dim3(BB * 96, 2), 384, 0, stream>>>(ws + QKVVT, ws + QKV,
                                                         ws + AVL);

    // ---- cAttn: ONE fused 1x1 conv (q|k|v, KU=4) -- QKV dead, QKC aliases ----
    conv_mfma<1, 6, 6, 4, 8><<<dim3(96, BB), 512, 0, stream>>>(
        ws + X32, ws + PK_C3, ws + QKC, ws + VCT, nullptr,
        (const float*)(ws + B3), 8);
    attn_c_k<<<dim3(96, 4, BB), 256, 0, stream>>>(ws + QKC, ws + VCT, ws + AVL);

    // ---- final conv (proven 2-phase, KU=2) + residual from x32 ----
    conv_mfma<9, 4, 5, 2, 4><<<dim3(96, BB), 512, 0, stream>>>(
        ws + AVL, ws + PK_FIN, nullptr, ws + X32, out, nullptr, 16);
}